// Round 7
// baseline (345.589 us; speedup 1.0000x reference)
//
#include <hip/hip_runtime.h>
#include <hip/hip_bf16.h>

#define NT   32768
#define NH   2048
#define NE   128
#define TOPK 8
#define BT   32
#define BND    6.0e-4f
#define TWO_B  (2.0f * BND)

// ws layout (bytes):
//   [0,64):          u32 flagged-token counter
//   [64, 64+1MB):    Wt: B-fragment-ordered split-bf16 W (16B chunk g: lane=g&63,
//                    te=(g>>6)&7, s=(g>>9)&1, k32=g>>10)
//   [64+1MB, ...):   records, 32B each: u32 token, u32 cnt, 16x u8 cand ids
#define WS_W_OFF   64
#define WS_REC_U32 262160     // (64 + 1MB)/4

typedef __attribute__((ext_vector_type(8))) short bf16x8;
typedef __attribute__((ext_vector_type(4))) float f32x4;
typedef __attribute__((ext_vector_type(4))) unsigned int u32x4;

static __device__ __forceinline__ unsigned short f2bf(float f) {
    __hip_bfloat16 h = __float2bfloat16(f);
    return *reinterpret_cast<unsigned short*>(&h);
}

// ---------------- K0: build B-fragment-ordered W hi/lo chunks (RNE split) ----------------
__global__ __launch_bounds__(256) void prep_w_kernel(
    const float* __restrict__ W, unsigned short* __restrict__ Wt)
{
    int g = blockIdx.x * 256 + threadIdx.x;   // 65536 16B-per-lane chunks
    int lane = g & 63;
    int te   = (g >> 6) & 7;
    int s    = (g >> 9) & 1;
    int k32  = g >> 10;
    int row  = te * 16 + (lane & 15);
    int kb   = k32 * 32 + (lane >> 4) * 8;
    const float* src = W + (size_t)row * NH + kb;
    float4 f0 = *(const float4*)src;
    float4 f1 = *(const float4*)(src + 4);
    float f[8] = {f0.x, f0.y, f0.z, f0.w, f1.x, f1.y, f1.z, f1.w};
    bf16x8 o;
    #pragma unroll
    for (int e = 0; e < 8; ++e) {
        unsigned short h = f2bf(f[e]);
        if (s == 0) o[e] = (short)h;
        else {
            float fh = __builtin_bit_cast(float, ((unsigned int)h) << 16);
            o[e] = (short)f2bf(f[e] - fh);
        }
    }
    *(bf16x8*)(Wt + (size_t)g * 8) = o;
}

// ---------------- K1: reg-dbuf prefetched split-bf16 MFMA GEMM -> raw logits ----------------
// 256 thr = 4 waves; wave w owns K-slice [w*512, w*512+512); 32 tokens/block.
__global__ __launch_bounds__(256, 2) void router_gemm_kernel(
    const float* __restrict__ X, const unsigned short* __restrict__ Wt,
    float* __restrict__ outLg)
{
    __shared__ float ps[2][BT * 132];   // 33.8 KB

    const int tid  = threadIdx.x;
    const int lane = tid & 63;
    const int w    = tid >> 6;           // 0..3
    const int l15  = lane & 15, lhi = lane >> 4;
    const int t0   = blockIdx.x * BT;

    f32x4 acc[2][8];
    #pragma unroll
    for (int i = 0; i < 2; ++i)
        #pragma unroll
        for (int te = 0; te < 8; ++te) acc[i][te] = (f32x4){0.f, 0.f, 0.f, 0.f};

    const float* x0 = X + (size_t)(t0 + l15) * NH + w * 512 + lhi * 8;
    const float* x1 = x0 + 16 * NH;
    const unsigned short* wbase = Wt + (size_t)(w * 16) * 8192 + lane * 8;

    bf16x8 b0[8][2], b1[8][2];

    #define LOADB(arr, kk) do {                                                \
        const unsigned short* wb_ = wbase + (size_t)(kk) * 8192;               \
        _Pragma("unroll")                                                      \
        for (int te = 0; te < 8; ++te) {                                       \
            arr[te][0] = *(const bf16x8*)(wb_ + te * 512);                     \
            arr[te][1] = *(const bf16x8*)(wb_ + 4096 + te * 512);              \
        }                                                                      \
    } while (0)

    // round-half-up bit-split: ~3.5 VALU/elem; |x-ah-al| <= 2^-18|x|
    #define SPLITA(kk, ah, al) do {                                            \
        _Pragma("unroll")                                                      \
        for (int i = 0; i < 2; ++i) {                                          \
            const float* xp = (i ? x1 : x0) + (kk) * 32;                       \
            float4 fa = *(const float4*)xp;                                    \
            float4 fb = *(const float4*)(xp + 4);                              \
            float ff[8] = {fa.x, fa.y, fa.z, fa.w, fb.x, fb.y, fb.z, fb.w};    \
            unsigned int hu[4], lu[4];                                         \
            _Pragma("unroll")                                                  \
            for (int p = 0; p < 4; ++p) {                                      \
                unsigned int u0 = __builtin_bit_cast(unsigned int, ff[2*p]);   \
                unsigned int u1 = __builtin_bit_cast(unsigned int, ff[2*p+1]); \
                unsigned int r0 = u0 + 0x8000u, r1 = u1 + 0x8000u;             \
                hu[p] = (r0 >> 16) | (r1 & 0xFFFF0000u);                       \
                float h0 = __builtin_bit_cast(float, r0 & 0xFFFF0000u);        \
                float h1 = __builtin_bit_cast(float, r1 & 0xFFFF0000u);        \
                float e0 = ff[2*p] - h0, e1 = ff[2*p+1] - h1;                  \
                unsigned int s0 = __builtin_bit_cast(unsigned int, e0) + 0x8000u; \
                unsigned int s1 = __builtin_bit_cast(unsigned int, e1) + 0x8000u; \
                lu[p] = (s0 >> 16) | (s1 & 0xFFFF0000u);                       \
            }                                                                  \
            ah[i] = __builtin_bit_cast(bf16x8, (u32x4){hu[0],hu[1],hu[2],hu[3]}); \
            al[i] = __builtin_bit_cast(bf16x8, (u32x4){lu[0],lu[1],lu[2],lu[3]}); \
        }                                                                      \
    } while (0)

    #define DOMFMA(b, ah, al) do {                                             \
        _Pragma("unroll")                                                      \
        for (int te = 0; te < 8; ++te) {                                       \
            acc[0][te] = __builtin_amdgcn_mfma_f32_16x16x32_bf16(ah[0], b[te][0], acc[0][te], 0, 0, 0); \
            acc[1][te] = __builtin_amdgcn_mfma_f32_16x16x32_bf16(ah[1], b[te][0], acc[1][te], 0, 0, 0); \
            acc[0][te] = __builtin_amdgcn_mfma_f32_16x16x32_bf16(al[0], b[te][0], acc[0][te], 0, 0, 0); \
            acc[1][te] = __builtin_amdgcn_mfma_f32_16x16x32_bf16(al[1], b[te][0], acc[1][te], 0, 0, 0); \
            acc[0][te] = __builtin_amdgcn_mfma_f32_16x16x32_bf16(ah[0], b[te][1], acc[0][te], 0, 0, 0); \
            acc[1][te] = __builtin_amdgcn_mfma_f32_16x16x32_bf16(ah[1], b[te][1], acc[1][te], 0, 0, 0); \
        }                                                                      \
    } while (0)

    LOADB(b0, 0);
    for (int p = 0; p < 8; ++p) {
        bf16x8 ah[2], al[2];
        LOADB(b1, 2 * p + 1);
        SPLITA(2 * p, ah, al);
        DOMFMA(b0, ah, al);
        if (p < 7) LOADB(b0, 2 * p + 2);
        SPLITA(2 * p + 1, ah, al);
        DOMFMA(b1, ah, al);
    }

    // ---- cross-wave K reduction ----
    if (w < 2) {
        #pragma unroll
        for (int i = 0; i < 2; ++i)
            #pragma unroll
            for (int te = 0; te < 8; ++te)
                #pragma unroll
                for (int q = 0; q < 4; ++q)
                    ps[w][(i * 16 + lhi * 4 + q) * 132 + te * 16 + l15] = acc[i][te][q];
    }
    __syncthreads();
    if (w >= 2) {
        #pragma unroll
        for (int i = 0; i < 2; ++i)
            #pragma unroll
            for (int te = 0; te < 8; ++te)
                #pragma unroll
                for (int q = 0; q < 4; ++q) {
                    int o = (i * 16 + lhi * 4 + q) * 132 + te * 16 + l15;
                    ps[w - 2][o] += acc[i][te][q];
                }
    }
    __syncthreads();
    // fold + coalesced store of raw f32 logits into the out scores region
    #pragma unroll
    for (int q = 0; q < 4; ++q) {
        int i = tid + q * 256;                 // 0..1023
        int row = i >> 5, c4 = i & 31;
        int o = row * 132 + c4 * 4;
        float4 a = *(float4*)&ps[0][o];
        float4 b = *(float4*)&ps[1][o];
        a.x += b.x; a.y += b.y; a.z += b.z; a.w += b.w;
        *(float4*)(outLg + (size_t)(t0 + row) * NE + c4 * 4) = a;
    }
}

// ---------------- K2: select/flag/scatter (reads logits from out, rewrites in place) ----------------
__global__ __launch_bounds__(64) void select_kernel(
    float* __restrict__ out, unsigned int* __restrict__ ws)
{
    const int tg = blockIdx.x * 64 + threadIdx.x;
    float* row = out + (size_t)tg * NE;

    float tv[13]; int ti[13];
    #pragma unroll
    for (int k = 0; k < 13; ++k) { tv[k] = -3.0e38f; ti[k] = 0; }

    #pragma unroll 4
    for (int c = 0; c < 32; ++c) {
        float4 v4 = *(const float4*)(row + c * 4);
        float vs[4] = {v4.x, v4.y, v4.z, v4.w};
        #pragma unroll
        for (int j = 0; j < 4; ++j) {
            float v = vs[j];
            if (v > tv[12]) {
                float cv = v; int ci = c * 4 + j;
                #pragma unroll
                for (int s = 0; s < 13; ++s) {
                    if (cv > tv[s]) {
                        float t1 = tv[s]; int t2 = ti[s];
                        tv[s] = cv; ti[s] = ci; cv = t1; ci = t2;
                    }
                }
            }
        }
    }

    bool flag = false;
    #pragma unroll
    for (int k = 0; k < 8; ++k) flag |= (tv[k] - tv[k + 1] < TWO_B);

    float pv[8]; float ksum = 0.f;
    #pragma unroll
    for (int k = 0; k < 8; ++k) { pv[k] = expf(tv[k] - tv[0]); ksum += pv[k]; }

    // rewrite row: zeros then scatter (program order to aliasing addrs preserved)
    float4 z = make_float4(0.f, 0.f, 0.f, 0.f);
    #pragma unroll
    for (int c = 0; c < 32; ++c) *(float4*)(row + c * 4) = z;
    #pragma unroll
    for (int k = 0; k < 8; ++k) row[ti[k]] = pv[k] / ksum;

    float* irow = out + (size_t)NT * NE + (size_t)tg * TOPK;
    float4 i0 = make_float4((float)ti[0], (float)ti[1], (float)ti[2], (float)ti[3]);
    float4 i1 = make_float4((float)ti[4], (float)ti[5], (float)ti[6], (float)ti[7]);
    *(float4*)irow = i0;
    *(float4*)(irow + 4) = i1;

    if (flag) {
        unsigned int cnt;
        unsigned int idw[4] = {0u, 0u, 0u, 0u};
        float thr = tv[7] - TWO_B;
        if (tv[12] >= thr) {
            cnt = 0xFFu;
        } else {
            cnt = 0;
            #pragma unroll
            for (int k = 0; k < 13; ++k) {
                if (k < 8 || tv[k] >= thr) {
                    idw[cnt >> 2] |= ((unsigned int)ti[k]) << ((cnt & 3) * 8);
                    ++cnt;
                }
            }
        }
        unsigned int slot = atomicAdd(ws, 1u);
        unsigned int* rec = ws + WS_REC_U32 + slot * 8;
        rec[0] = (unsigned int)tg;
        rec[1] = cnt;
        rec[2] = idw[0]; rec[3] = idw[1]; rec[4] = idw[2]; rec[5] = idw[3];
    }
}

// ---------------- K3: f64 refine flagged tokens ----------------
__global__ __launch_bounds__(256) void finalize_kernel(
    const float* __restrict__ X, const float* __restrict__ W,
    float* __restrict__ out, const unsigned int* __restrict__ ws)
{
    __shared__ float  xs[2048];
    __shared__ double cv[128];
    __shared__ int    cid[128];
    __shared__ float  ovals[8];
    __shared__ int    oidx[8];

    const int tid = threadIdx.x;
    const int lane = tid & 63, w = tid >> 6;
    const unsigned int n = ws[0];

    for (unsigned int rI = blockIdx.x; rI < n; rI += gridDim.x) {
        const unsigned int* rec = ws + WS_REC_U32 + rI * 8;
        const int tg = (int)rec[0];
        const unsigned int cnt = rec[1];
        const unsigned char* ids = (const unsigned char*)(rec + 2);
        const int nc = (cnt == 0xFFu) ? NE : (int)cnt;

        #pragma unroll
        for (int q = 0; q < 2; ++q) {
            int i = tid + q * 256;
            *(float4*)(xs + i * 4) = *(const float4*)(X + (size_t)tg * NH + i * 4);
        }
        __syncthreads();

        for (int c = w; c < nc; c += 4) {
            int e = (cnt == 0xFFu) ? c : (int)ids[c];
            const float* wrow = W + (size_t)e * NH;
            double s = 0.0;
            #pragma unroll
            for (int m = 0; m < 8; ++m) {
                float4 wv = *(const float4*)(wrow + m * 256 + lane * 4);
                float4 xv = *(const float4*)(xs + m * 256 + lane * 4);
                s = fma((double)xv.x, (double)wv.x, s);
                s = fma((double)xv.y, (double)wv.y, s);
                s = fma((double)xv.z, (double)wv.z, s);
                s = fma((double)xv.w, (double)wv.w, s);
            }
            #pragma unroll
            for (int off = 32; off >= 1; off >>= 1) s += __shfl_xor(s, off);
            if (lane == 0) { cv[c] = s; cid[c] = e; }
        }
        __syncthreads();

        if (tid == 0) {
            double lv[8];
            #pragma unroll
            for (int k = 0; k < 8; ++k) {
                double best = -1.0e300; int bi = 1 << 30, bc = 0;
                for (int c = 0; c < nc; ++c) {
                    double v = cv[c]; int e = cid[c];
                    if (v > best || (v == best && e < bi)) { best = v; bi = e; bc = c; }
                }
                lv[k] = best; oidx[k] = bi; cv[bc] = -1.0e301;
            }
            double m = lv[0], sum = 0.0, p[8];
            #pragma unroll
            for (int k = 0; k < 8; ++k) { p[k] = exp(lv[k] - m); sum += p[k]; }
            #pragma unroll
            for (int k = 0; k < 8; ++k) ovals[k] = (float)(p[k] / sum);
        }
        __syncthreads();

        float* srow = out + (size_t)tg * NE;
        if (tid < NE) {
            float val = 0.f;
            #pragma unroll
            for (int k = 0; k < 8; ++k) if (oidx[k] == tid) val = ovals[k];
            srow[tid] = val;
        }
        if (tid < TOPK) out[(size_t)NT * NE + (size_t)tg * TOPK + tid] = (float)oidx[tid];
        __syncthreads();
    }
}

extern "C" void kernel_launch(void* const* d_in, const int* in_sizes, int n_in,
                              void* d_out, int out_size, void* d_ws, size_t ws_size,
                              hipStream_t stream) {
    const float* X = (const float*)d_in[0];
    const float* W = (const float*)d_in[1];
    float* out = (float*)d_out;
    unsigned char* wsb = (unsigned char*)d_ws;
    unsigned short* Wt = (unsigned short*)(wsb + WS_W_OFF);

    hipMemsetAsync(d_ws, 0, 64, stream);
    prep_w_kernel<<<256, 256, 0, stream>>>(W, Wt);
    router_gemm_kernel<<<NT / BT, 256, 0, stream>>>(X, Wt, out);
    select_kernel<<<NT / 64, 64, 0, stream>>>(out, (unsigned int*)d_ws);
    finalize_kernel<<<1024, 256, 0, stream>>>(X, W, out, (const unsigned int*)d_ws);
}

// Round 8
// 221.651 us; speedup vs baseline: 1.5592x; 1.5592x over previous
//
#include <hip/hip_runtime.h>
#include <hip/hip_bf16.h>

#define NT   32768
#define NH   2048
#define NE   128
#define TOPK 8
#define BT   32
#define BND    6.0e-4f
#define TWO_B  (2.0f * BND)

// ws layout (bytes):
//   [0,64):          u32 flagged-token counter
//   [64, 64+1MB):    Wt: B-fragment-ordered split-bf16 W (16B chunk g: lane=g&63,
//                    te=(g>>6)&7, s=(g>>9)&1, k32=g>>10)
//   [64+1MB, ...):   records, 32B each: u32 token, u32 cnt, 16x u8 cand ids
#define WS_W_OFF   64
#define WS_REC_U32 262160     // (64 + 1MB)/4

typedef __attribute__((ext_vector_type(8))) short bf16x8;
typedef __attribute__((ext_vector_type(4))) float f32x4;
typedef __attribute__((ext_vector_type(4))) unsigned int u32x4;

static __device__ __forceinline__ unsigned short f2bf(float f) {
    __hip_bfloat16 h = __float2bfloat16(f);
    return *reinterpret_cast<unsigned short*>(&h);
}

// ---------------- K0: build B-fragment-ordered W hi/lo chunks (RNE split) ----------------
__global__ __launch_bounds__(256) void prep_w_kernel(
    const float* __restrict__ W, unsigned short* __restrict__ Wt)
{
    int g = blockIdx.x * 256 + threadIdx.x;   // 65536 16B-per-lane chunks
    int lane = g & 63;
    int te   = (g >> 6) & 7;
    int s    = (g >> 9) & 1;
    int k32  = g >> 10;
    int row  = te * 16 + (lane & 15);
    int kb   = k32 * 32 + (lane >> 4) * 8;
    const float* src = W + (size_t)row * NH + kb;
    float4 f0 = *(const float4*)src;
    float4 f1 = *(const float4*)(src + 4);
    float f[8] = {f0.x, f0.y, f0.z, f0.w, f1.x, f1.y, f1.z, f1.w};
    bf16x8 o;
    #pragma unroll
    for (int e = 0; e < 8; ++e) {
        unsigned short h = f2bf(f[e]);
        if (s == 0) o[e] = (short)h;
        else {
            float fh = __builtin_bit_cast(float, ((unsigned int)h) << 16);
            o[e] = (short)f2bf(f[e] - fh);
        }
    }
    *(bf16x8*)(Wt + (size_t)g * 8) = o;
}

// ---------------- K1: reg-dbuf prefetched split-bf16 MFMA GEMM + fused select ----------------
// 256 thr = 4 waves; wave w owns K-slice [w*512, w*512+512); 32 tokens/block.
__global__ __launch_bounds__(256, 2) void router_gemm_kernel(
    const float* __restrict__ X, const unsigned short* __restrict__ Wt,
    float* __restrict__ out, unsigned int* __restrict__ ws)
{
    __shared__ float ps[2][BT * 132];   // 33.8 KB

    const int tid  = threadIdx.x;
    const int lane = tid & 63;
    const int w    = tid >> 6;           // 0..3
    const int l15  = lane & 15, lhi = lane >> 4;
    const int t0   = blockIdx.x * BT;

    f32x4 acc[2][8];
    #pragma unroll
    for (int i = 0; i < 2; ++i)
        #pragma unroll
        for (int te = 0; te < 8; ++te) acc[i][te] = (f32x4){0.f, 0.f, 0.f, 0.f};

    const float* x0 = X + (size_t)(t0 + l15) * NH + w * 512 + lhi * 8;
    const float* x1 = x0 + 16 * NH;
    const unsigned short* wbase = Wt + (size_t)(w * 16) * 8192 + lane * 8;

    bf16x8 b0[8][2], b1[8][2];

    #define LOADB(arr, kk) do {                                                \
        const unsigned short* wb_ = wbase + (size_t)(kk) * 8192;               \
        _Pragma("unroll")                                                      \
        for (int te = 0; te < 8; ++te) {                                       \
            arr[te][0] = *(const bf16x8*)(wb_ + te * 512);                     \
            arr[te][1] = *(const bf16x8*)(wb_ + 4096 + te * 512);              \
        }                                                                      \
    } while (0)

    // round-half-up bit-split: ~3.5 VALU/elem; |x-ah-al| <= 2^-18|x|
    #define SPLITA(kk, ah, al) do {                                            \
        _Pragma("unroll")                                                      \
        for (int i = 0; i < 2; ++i) {                                          \
            const float* xp = (i ? x1 : x0) + (kk) * 32;                       \
            float4 fa = *(const float4*)xp;                                    \
            float4 fb = *(const float4*)(xp + 4);                              \
            float ff[8] = {fa.x, fa.y, fa.z, fa.w, fb.x, fb.y, fb.z, fb.w};    \
            unsigned int hu[4], lu[4];                                         \
            _Pragma("unroll")                                                  \
            for (int p = 0; p < 4; ++p) {                                      \
                unsigned int u0 = __builtin_bit_cast(unsigned int, ff[2*p]);   \
                unsigned int u1 = __builtin_bit_cast(unsigned int, ff[2*p+1]); \
                unsigned int r0 = u0 + 0x8000u, r1 = u1 + 0x8000u;             \
                hu[p] = (r0 >> 16) | (r1 & 0xFFFF0000u);                       \
                float h0 = __builtin_bit_cast(float, r0 & 0xFFFF0000u);        \
                float h1 = __builtin_bit_cast(float, r1 & 0xFFFF0000u);        \
                float e0 = ff[2*p] - h0, e1 = ff[2*p+1] - h1;                  \
                unsigned int s0 = __builtin_bit_cast(unsigned int, e0) + 0x8000u; \
                unsigned int s1 = __builtin_bit_cast(unsigned int, e1) + 0x8000u; \
                lu[p] = (s0 >> 16) | (s1 & 0xFFFF0000u);                       \
            }                                                                  \
            ah[i] = __builtin_bit_cast(bf16x8, (u32x4){hu[0],hu[1],hu[2],hu[3]}); \
            al[i] = __builtin_bit_cast(bf16x8, (u32x4){lu[0],lu[1],lu[2],lu[3]}); \
        }                                                                      \
    } while (0)

    #define DOMFMA(b, ah, al) do {                                             \
        _Pragma("unroll")                                                      \
        for (int te = 0; te < 8; ++te) {                                       \
            acc[0][te] = __builtin_amdgcn_mfma_f32_16x16x32_bf16(ah[0], b[te][0], acc[0][te], 0, 0, 0); \
            acc[1][te] = __builtin_amdgcn_mfma_f32_16x16x32_bf16(ah[1], b[te][0], acc[1][te], 0, 0, 0); \
            acc[0][te] = __builtin_amdgcn_mfma_f32_16x16x32_bf16(al[0], b[te][0], acc[0][te], 0, 0, 0); \
            acc[1][te] = __builtin_amdgcn_mfma_f32_16x16x32_bf16(al[1], b[te][0], acc[1][te], 0, 0, 0); \
            acc[0][te] = __builtin_amdgcn_mfma_f32_16x16x32_bf16(ah[0], b[te][1], acc[0][te], 0, 0, 0); \
            acc[1][te] = __builtin_amdgcn_mfma_f32_16x16x32_bf16(ah[1], b[te][1], acc[1][te], 0, 0, 0); \
        }                                                                      \
    } while (0)

    LOADB(b0, 0);
    for (int p = 0; p < 8; ++p) {
        bf16x8 ah[2], al[2];
        LOADB(b1, 2 * p + 1);
        SPLITA(2 * p, ah, al);
        DOMFMA(b0, ah, al);
        if (p < 7) LOADB(b0, 2 * p + 2);
        SPLITA(2 * p + 1, ah, al);
        DOMFMA(b1, ah, al);
    }

    // ---- cross-wave K reduction ----
    if (w < 2) {
        #pragma unroll
        for (int i = 0; i < 2; ++i)
            #pragma unroll
            for (int te = 0; te < 8; ++te)
                #pragma unroll
                for (int q = 0; q < 4; ++q)
                    ps[w][(i * 16 + lhi * 4 + q) * 132 + te * 16 + l15] = acc[i][te][q];
    }
    __syncthreads();
    if (w >= 2) {
        #pragma unroll
        for (int i = 0; i < 2; ++i)
            #pragma unroll
            for (int te = 0; te < 8; ++te)
                #pragma unroll
                for (int q = 0; q < 4; ++q) {
                    int o = (i * 16 + lhi * 4 + q) * 132 + te * 16 + l15;
                    ps[w - 2][o] += acc[i][te][q];
                }
    }
    __syncthreads();
    // fold slice1 into slice0
    #pragma unroll
    for (int q = 0; q < 4; ++q) {
        int idx = tid + q * 256;                 // 0..1023
        int row = idx >> 5, c4 = idx & 31;
        int o = row * 132 + c4 * 4;
        float4 a = *(float4*)&ps[0][o];
        float4 b = *(float4*)&ps[1][o];
        a.x += b.x; a.y += b.y; a.z += b.z; a.w += b.w;
        *(float4*)&ps[0][o] = a;
    }
    // zero this block's dense score rows (32x128 f32)
    float* scoreBase = out + (size_t)t0 * NE;
    #pragma unroll
    for (int q = 0; q < 4; ++q) {
        int i = tid + q * 256;
        *(float4*)(scoreBase + (size_t)i * 4) = make_float4(0.f, 0.f, 0.f, 0.f);
    }
    __syncthreads();

    // ---- per-token epilogue: top-13 insert-sort, gap check, flag ----
    if (tid < BT) {
        const float* row = &ps[0][tid * 132];
        float tv[13]; int ti[13];
        #pragma unroll
        for (int k = 0; k < 13; ++k) { tv[k] = -3.0e38f; ti[k] = 0; }
        for (int e = 0; e < NE; ++e) {
            float v = row[e];
            if (v > tv[12]) {
                float cv = v; int ci = e;
                #pragma unroll
                for (int s = 0; s < 13; ++s) {
                    if (cv > tv[s]) {
                        float t1 = tv[s]; int t2 = ti[s];
                        tv[s] = cv; ti[s] = ci; cv = t1; ci = t2;
                    }
                }
            }
        }
        bool flag = false;
        #pragma unroll
        for (int k = 0; k < 8; ++k) flag |= (tv[k] - tv[k + 1] < TWO_B);

        float pv[8]; float ksum = 0.f;
        #pragma unroll
        for (int k = 0; k < 8; ++k) { pv[k] = expf(tv[k] - tv[0]); ksum += pv[k]; }
        const int tg = t0 + tid;
        float* srow = out + (size_t)tg * NE;
        float* irow = out + (size_t)NT * NE + (size_t)tg * TOPK;
        #pragma unroll
        for (int k = 0; k < 8; ++k) {
            srow[ti[k]] = pv[k] / ksum;
            irow[k] = (float)ti[k];
        }

        if (flag) {
            unsigned int cnt;
            unsigned int idw[4] = {0u, 0u, 0u, 0u};
            float thr = tv[7] - TWO_B;
            if (tv[12] >= thr) {
                cnt = 0xFFu;
            } else {
                cnt = 0;
                #pragma unroll
                for (int k = 0; k < 13; ++k) {
                    if (k < 8 || tv[k] >= thr) {
                        idw[cnt >> 2] |= ((unsigned int)ti[k]) << ((cnt & 3) * 8);
                        ++cnt;
                    }
                }
            }
            unsigned int slot = atomicAdd(ws, 1u);
            unsigned int* rec = ws + WS_REC_U32 + slot * 8;
            rec[0] = (unsigned int)tg;
            rec[1] = cnt;
            rec[2] = idw[0]; rec[3] = idw[1]; rec[4] = idw[2]; rec[5] = idw[3];
        }
    }
}

// ---------------- K2: f64 refine flagged tokens ----------------
__global__ __launch_bounds__(256) void finalize_kernel(
    const float* __restrict__ X, const float* __restrict__ W,
    float* __restrict__ out, const unsigned int* __restrict__ ws)
{
    __shared__ float  xs[2048];
    __shared__ double cv[128];
    __shared__ int    cid[128];
    __shared__ float  ovals[8];
    __shared__ int    oidx[8];

    const int tid = threadIdx.x;
    const int lane = tid & 63, w = tid >> 6;
    const unsigned int n = ws[0];

    for (unsigned int rI = blockIdx.x; rI < n; rI += gridDim.x) {
        const unsigned int* rec = ws + WS_REC_U32 + rI * 8;
        const int tg = (int)rec[0];
        const unsigned int cnt = rec[1];
        const unsigned char* ids = (const unsigned char*)(rec + 2);
        const int nc = (cnt == 0xFFu) ? NE : (int)cnt;

        #pragma unroll
        for (int q = 0; q < 2; ++q) {
            int i = tid + q * 256;
            *(float4*)(xs + i * 4) = *(const float4*)(X + (size_t)tg * NH + i * 4);
        }
        __syncthreads();

        for (int c = w; c < nc; c += 4) {
            int e = (cnt == 0xFFu) ? c : (int)ids[c];
            const float* wrow = W + (size_t)e * NH;
            double s = 0.0;
            #pragma unroll
            for (int m = 0; m < 8; ++m) {
                float4 wv = *(const float4*)(wrow + m * 256 + lane * 4);
                float4 xv = *(const float4*)(xs + m * 256 + lane * 4);
                s = fma((double)xv.x, (double)wv.x, s);
                s = fma((double)xv.y, (double)wv.y, s);
                s = fma((double)xv.z, (double)wv.z, s);
                s = fma((double)xv.w, (double)wv.w, s);
            }
            #pragma unroll
            for (int off = 32; off >= 1; off >>= 1) s += __shfl_xor(s, off);
            if (lane == 0) { cv[c] = s; cid[c] = e; }
        }
        __syncthreads();

        if (tid == 0) {
            double lv[8];
            #pragma unroll
            for (int k = 0; k < 8; ++k) {
                double best = -1.0e300; int bi = 1 << 30, bc = 0;
                for (int c = 0; c < nc; ++c) {
                    double v = cv[c]; int e = cid[c];
                    if (v > best || (v == best && e < bi)) { best = v; bi = e; bc = c; }
                }
                lv[k] = best; oidx[k] = bi; cv[bc] = -1.0e301;
            }
            double m = lv[0], sum = 0.0, p[8];
            #pragma unroll
            for (int k = 0; k < 8; ++k) { p[k] = exp(lv[k] - m); sum += p[k]; }
            #pragma unroll
            for (int k = 0; k < 8; ++k) ovals[k] = (float)(p[k] / sum);
        }
        __syncthreads();

        float* srow = out + (size_t)tg * NE;
        if (tid < NE) {
            float val = 0.f;
            #pragma unroll
            for (int k = 0; k < 8; ++k) if (oidx[k] == tid) val = ovals[k];
            srow[tid] = val;
        }
        if (tid < TOPK) out[(size_t)NT * NE + (size_t)tg * TOPK + tid] = (float)oidx[tid];
        __syncthreads();
    }
}

extern "C" void kernel_launch(void* const* d_in, const int* in_sizes, int n_in,
                              void* d_out, int out_size, void* d_ws, size_t ws_size,
                              hipStream_t stream) {
    const float* X = (const float*)d_in[0];
    const float* W = (const float*)d_in[1];
    float* out = (float*)d_out;
    unsigned char* wsb = (unsigned char*)d_ws;
    unsigned short* Wt = (unsigned short*)(wsb + WS_W_OFF);

    hipMemsetAsync(d_ws, 0, 64, stream);
    prep_w_kernel<<<256, 256, 0, stream>>>(W, Wt);
    router_gemm_kernel<<<NT / BT, 256, 0, stream>>>(X, Wt, out, (unsigned int*)d_ws);
    finalize_kernel<<<1024, 256, 0, stream>>>(X, W, out, (const unsigned int*)d_ws);
}